// Round 1
// baseline (253.045 us; speedup 1.0000x reference)
//
#include <hip/hip_runtime.h>
#include <hip/hip_bf16.h>

#define N_TOK 4096
#define NH 8
#define HD 32
#define CDIM 256
#define QKV_N 768
#define SCALE_F 0.17677669529663687f  // 32^-0.5

typedef float  f32x4  __attribute__((ext_vector_type(4)));
typedef int    i32x4  __attribute__((ext_vector_type(4)));
typedef short  s16x4  __attribute__((ext_vector_type(4)));
typedef __bf16 bf16x8 __attribute__((ext_vector_type(8)));

union FragI { i32x4 i; bf16x8 b; };
union FragH { struct { s16x4 lo, hi; } s; bf16x8 b; };

// ---------------------------------------------------------------------------
// keep mask: keep = 3x3 neighborhood OR of (dbz >= 15), per frame (zero pad).
// bias = 0 (keep) / -30000 (masked key -> exp underflows to exact 0).
__global__ __launch_bounds__(256) void prep_mask(const float* __restrict__ dbz,
                                                 float* __restrict__ bias,
                                                 int* __restrict__ keepi) {
  int n = blockIdx.x * 256 + threadIdx.x;
  if (n >= N_TOK) return;
  int t = n >> 10, rc = n & 1023, r = rc >> 5, c = rc & 31;
  bool keep = false;
  #pragma unroll
  for (int dr = -1; dr <= 1; dr++) {
    #pragma unroll
    for (int dc = -1; dc <= 1; dc++) {
      int rr = r + dr, cc = c + dc;
      if (rr >= 0 && rr < 32 && cc >= 0 && cc < 32)
        keep = keep || (dbz[t * 1024 + rr * 32 + cc] >= 15.0f);
    }
  }
  bias[n]  = keep ? 0.0f : -30000.0f;
  keepi[n] = keep ? 1 : 0;
}

// ---------------------------------------------------------------------------
// fp32 -> bf16 convert; first n_scaled elements multiplied by scale.
__global__ __launch_bounds__(256) void cvt_bf16(const float* __restrict__ src,
                                                __bf16* __restrict__ dst,
                                                int n, int n_scaled, float scale) {
  int i = blockIdx.x * 256 + threadIdx.x;
  if (i >= n) return;
  float v = src[i];
  if (i < n_scaled) v *= scale;
  dst[i] = (__bf16)v;
}

// ---------------------------------------------------------------------------
// QKV GEMM: (4096 x 256) @ (768 x 256)^T via mfma 16x16x32 bf16.
// Block = 4 waves; wave computes 16(M) x 64(N). Epilogue packs:
//   q -> [h][n][d] (rows of Q, SCALE pre-folded into weights)
//   k -> [h][n][d]
//   v -> [h][d][n] (transposed, so attention V-frag loads are contiguous)
__global__ __launch_bounds__(256) void qkv_gemm(const __bf16* __restrict__ xb,
                                                const __bf16* __restrict__ wb,
                                                __bf16* __restrict__ qb,
                                                __bf16* __restrict__ kb,
                                                __bf16* __restrict__ vt) {
  int wave = threadIdx.x >> 6, lane = threadIdx.x & 63;
  int quad = lane >> 4, l16 = lane & 15;
  int m0 = blockIdx.x * 64 + wave * 16;
  int n0 = blockIdx.y * 64;

  f32x4 acc[4] = {};
  for (int kk = 0; kk < CDIM; kk += 32) {
    FragI af;
    af.i = *(const i32x4*)(xb + (size_t)(m0 + l16) * CDIM + kk + quad * 8);
    #pragma unroll
    for (int nt = 0; nt < 4; nt++) {
      FragI bfr;
      bfr.i = *(const i32x4*)(wb + (size_t)(n0 + nt * 16 + l16) * CDIM + kk + quad * 8);
      acc[nt] = __builtin_amdgcn_mfma_f32_16x16x32_bf16(af.b, bfr.b, acc[nt], 0, 0, 0);
    }
  }
  #pragma unroll
  for (int nt = 0; nt < 4; nt++) {
    int c = n0 + nt * 16 + l16;            // output channel in [0,768)
    int which = c >> 8, rem = c & 255, head = rem >> 5, d = rem & 31;
    #pragma unroll
    for (int r = 0; r < 4; r++) {
      int m = m0 + quad * 4 + r;           // token
      __bf16 v = (__bf16)acc[nt][r];
      if (which == 0)      qb[((size_t)head * N_TOK + m) * HD + d] = v;
      else if (which == 1) kb[((size_t)head * N_TOK + m) * HD + d] = v;
      else                 vt[((size_t)head * HD + d) * N_TOK + m] = v;
    }
  }
}

// ---------------------------------------------------------------------------
// Flash attention. One wave = 16 queries of one head; 32 keys/step.
// S^T = K * Q^T (so C-layout col = query -> softmax stats need only 2 shfl_xor).
// P enters the PV mfma as an A-frag built in-register with key permutation
// pi(slot 8Q+j) = {4Q+j (j<4), 16+4Q+j-4 (j>=4)}; V frags use the same pi.
__global__ __launch_bounds__(256) void attn_kernel(const __bf16* __restrict__ qb,
                                                   const __bf16* __restrict__ kb,
                                                   const __bf16* __restrict__ vt,
                                                   const float* __restrict__ bias,
                                                   __bf16* __restrict__ ob) {
  int head = blockIdx.y;
  int wave = threadIdx.x >> 6, lane = threadIdx.x & 63;
  int quad = lane >> 4, l16 = lane & 15;
  int q0 = blockIdx.x * 64 + wave * 16;

  const __bf16* qh = qb + (size_t)head * N_TOK * HD;
  const __bf16* kh = kb + (size_t)head * N_TOK * HD;
  const __bf16* vh = vt + (size_t)head * HD * N_TOK;

  FragI qf;
  qf.i = *(const i32x4*)(qh + (size_t)(q0 + l16) * HD + quad * 8);

  float m_run = -INFINITY, l_run = 0.0f;
  f32x4 o_lo = {0.f, 0.f, 0.f, 0.f}, o_hi = {0.f, 0.f, 0.f, 0.f};

  for (int k0 = 0; k0 < N_TOK; k0 += 32) {
    FragI ka, kb2;
    ka.i  = *(const i32x4*)(kh + (size_t)(k0 + l16) * HD + quad * 8);
    kb2.i = *(const i32x4*)(kh + (size_t)(k0 + 16 + l16) * HD + quad * 8);
    f32x4 z = {0.f, 0.f, 0.f, 0.f};
    // S^T tiles: D[key][q]; lane holds q = l16, keys quad*4+r (a) / 16+quad*4+r (b)
    f32x4 sa = __builtin_amdgcn_mfma_f32_16x16x32_bf16(ka.b,  qf.b, z, 0, 0, 0);
    f32x4 sb = __builtin_amdgcn_mfma_f32_16x16x32_bf16(kb2.b, qf.b, z, 0, 0, 0);

    f32x4 ba = *(const f32x4*)(bias + k0 + quad * 4);
    f32x4 bb = *(const f32x4*)(bias + k0 + 16 + quad * 4);

    float s[8];
    #pragma unroll
    for (int r = 0; r < 4; r++) { s[r] = sa[r] + ba[r]; s[4 + r] = sb[r] + bb[r]; }

    float mt = s[0];
    #pragma unroll
    for (int j = 1; j < 8; j++) mt = fmaxf(mt, s[j]);
    mt = fmaxf(mt, __shfl_xor(mt, 16));
    mt = fmaxf(mt, __shfl_xor(mt, 32));     // per-query max, uniform across quads

    float m_new = fmaxf(m_run, mt);
    float alpha = __expf(m_run - m_new);    // m_run=-inf first iter -> alpha=0, no NaN
    m_run = m_new;

    float p[8], psum = 0.0f;
    #pragma unroll
    for (int j = 0; j < 8; j++) { p[j] = __expf(s[j] - m_new); psum += p[j]; }
    psum += __shfl_xor(psum, 16);
    psum += __shfl_xor(psum, 32);
    l_run = l_run * alpha + psum;

    FragI pf;
    #pragma unroll
    for (int j = 0; j < 8; j++) pf.b[j] = (__bf16)p[j];

    // V frags (d = l16 and d = 16+l16), same key permutation as pf
    FragH vlo, vhi;
    const __bf16* vp = vh + (size_t)l16 * N_TOK + k0 + quad * 4;
    vlo.s.lo = *(const s16x4*)(vp);
    vlo.s.hi = *(const s16x4*)(vp + 16);
    const __bf16* vp2 = vh + (size_t)(16 + l16) * N_TOK + k0 + quad * 4;
    vhi.s.lo = *(const s16x4*)(vp2);
    vhi.s.hi = *(const s16x4*)(vp2 + 16);

    // rescale O rows (row = query quad*4+r) by alpha of that query
    #pragma unroll
    for (int r = 0; r < 4; r++) {
      float ar = __shfl(alpha, quad * 4 + r);
      o_lo[r] *= ar;
      o_hi[r] *= ar;
    }
    o_lo = __builtin_amdgcn_mfma_f32_16x16x32_bf16(pf.b, vlo.b, o_lo, 0, 0, 0);
    o_hi = __builtin_amdgcn_mfma_f32_16x16x32_bf16(pf.b, vhi.b, o_hi, 0, 0, 0);
  }

  #pragma unroll
  for (int r = 0; r < 4; r++) {
    float lr = __shfl(l_run, quad * 4 + r);
    float inv = 1.0f / lr;
    int m = q0 + quad * 4 + r;
    ob[(size_t)m * CDIM + head * HD + l16]      = (__bf16)(o_lo[r] * inv);
    ob[(size_t)m * CDIM + head * HD + 16 + l16] = (__bf16)(o_hi[r] * inv);
  }
}

// ---------------------------------------------------------------------------
// Output projection: out = (keep ? attn@Wp^T + b : 0) + x   (fp32 out)
__global__ __launch_bounds__(256) void proj_gemm(const __bf16* __restrict__ ob,
                                                 const __bf16* __restrict__ wb,
                                                 const float* __restrict__ pb,
                                                 const int* __restrict__ keepi,
                                                 const float* __restrict__ x,
                                                 float* __restrict__ out) {
  int wave = threadIdx.x >> 6, lane = threadIdx.x & 63;
  int quad = lane >> 4, l16 = lane & 15;
  int m0 = blockIdx.x * 64 + wave * 16;
  int n0 = blockIdx.y * 64;

  f32x4 acc[4] = {};
  for (int kk = 0; kk < CDIM; kk += 32) {
    FragI af;
    af.i = *(const i32x4*)(ob + (size_t)(m0 + l16) * CDIM + kk + quad * 8);
    #pragma unroll
    for (int nt = 0; nt < 4; nt++) {
      FragI bfr;
      bfr.i = *(const i32x4*)(wb + (size_t)(n0 + nt * 16 + l16) * CDIM + kk + quad * 8);
      acc[nt] = __builtin_amdgcn_mfma_f32_16x16x32_bf16(af.b, bfr.b, acc[nt], 0, 0, 0);
    }
  }
  #pragma unroll
  for (int nt = 0; nt < 4; nt++) {
    int c = n0 + nt * 16 + l16;
    #pragma unroll
    for (int r = 0; r < 4; r++) {
      int m = m0 + quad * 4 + r;
      float v = acc[nt][r] + pb[c];
      v = keepi[m] ? v : 0.0f;
      out[(size_t)m * CDIM + c] = v + x[(size_t)m * CDIM + c];
    }
  }
}

// ---------------------------------------------------------------------------
extern "C" void kernel_launch(void* const* d_in, const int* in_sizes, int n_in,
                              void* d_out, int out_size, void* d_ws, size_t ws_size,
                              hipStream_t stream) {
  const float* x      = (const float*)d_in[0];
  const float* dbz    = (const float*)d_in[1];
  const float* qkv_w  = (const float*)d_in[2];
  const float* proj_w = (const float*)d_in[3];
  const float* proj_b = (const float*)d_in[4];
  float* out = (float*)d_out;

  char* w = (char*)d_ws;
  __bf16* xb     = (__bf16*)(w);                       // 2 MB
  __bf16* qb     = (__bf16*)(w + (2u << 20));          // 2 MB
  __bf16* kb     = (__bf16*)(w + (4u << 20));          // 2 MB
  __bf16* vt     = (__bf16*)(w + (6u << 20));          // 2 MB
  __bf16* ob     = (__bf16*)(w + (8u << 20));          // 2 MB
  __bf16* wqkvb  = (__bf16*)(w + (10u << 20));         // 384 KB
  __bf16* wprojb = (__bf16*)(w + (10u << 20) + 393216);  // 128 KB
  float*  bias   = (float*)(w + (10u << 20) + 393216 + 131072);
  int*    keepi  = (int*)(w + (10u << 20) + 393216 + 131072 + 16384);

  prep_mask<<<dim3(16), dim3(256), 0, stream>>>(dbz, bias, keepi);
  cvt_bf16<<<dim3((N_TOK * CDIM + 255) / 256), dim3(256), 0, stream>>>(
      x, xb, N_TOK * CDIM, 0, 1.0f);
  cvt_bf16<<<dim3((QKV_N * CDIM + 255) / 256), dim3(256), 0, stream>>>(
      qkv_w, wqkvb, QKV_N * CDIM, CDIM * CDIM, SCALE_F);  // scale Q rows
  cvt_bf16<<<dim3((CDIM * CDIM + 255) / 256), dim3(256), 0, stream>>>(
      proj_w, wprojb, CDIM * CDIM, 0, 1.0f);

  qkv_gemm<<<dim3(N_TOK / 64, QKV_N / 64), dim3(256), 0, stream>>>(
      xb, wqkvb, qb, kb, vt);
  attn_kernel<<<dim3(N_TOK / 64, NH), dim3(256), 0, stream>>>(
      qb, kb, vt, bias, ob);
  proj_gemm<<<dim3(N_TOK / 64, CDIM / 64), dim3(256), 0, stream>>>(
      ob, wprojb, proj_b, keepi, x, out);
}